// Round 2
// baseline (1689.324 us; speedup 1.0000x reference)
//
#include <hip/hip_runtime.h>

#define NB 8192
#define ND 512
#define QB 32
#define KB 64
#define NT (NB / KB)

typedef unsigned short u16;
typedef unsigned int u32;
typedef __attribute__((ext_vector_type(8))) short bf16x8;
typedef __attribute__((ext_vector_type(4))) float f32x4;

__device__ inline u16 f2bf(float f) {
  u32 u = __float_as_uint(f);
  return (u16)((u + 0x7fffu + ((u >> 16) & 1u)) >> 16);
}

// ---------------- prep1: normalized bf16 rows ----------------
// xbf[b][d] = bf16( x[b][d] / max(||x_b||, eps) )
__global__ __launch_bounds__(256) void prep_kernel(const float* __restrict__ x,
                                                   u16* __restrict__ xbf) {
  int row = blockIdx.x * 4 + (threadIdx.x >> 6);
  int lane = threadIdx.x & 63;
  const float4* xr = reinterpret_cast<const float4*>(x + (size_t)row * ND);
  float4 a = xr[lane];
  float4 b = xr[64 + lane];
  float ss = a.x * a.x + a.y * a.y + a.z * a.z + a.w * a.w +
             b.x * b.x + b.y * b.y + b.z * b.z + b.w * b.w;
  ss += __shfl_xor(ss, 1);  ss += __shfl_xor(ss, 2);  ss += __shfl_xor(ss, 4);
  ss += __shfl_xor(ss, 8);  ss += __shfl_xor(ss, 16); ss += __shfl_xor(ss, 32);
  float rn = 1.0f / fmaxf(sqrtf(ss), 1e-12f);

  u16* dst = xbf + (size_t)row * ND;
  ushort4 ua = {f2bf(a.x * rn), f2bf(a.y * rn), f2bf(a.z * rn), f2bf(a.w * rn)};
  ushort4 ub = {f2bf(b.x * rn), f2bf(b.y * rn), f2bf(b.z * rn), f2bf(b.w * rn)};
  reinterpret_cast<ushort4*>(dst)[lane] = ua;
  reinterpret_cast<ushort4*>(dst)[64 + lane] = ub;
}

// ---------------- prep2: raw bf16 transpose xT[d][b] ----------------
// tile 64 b-rows x 32 d-cols, 256 threads
__global__ __launch_bounds__(256) void transpose_kernel(const float* __restrict__ x,
                                                        u16* __restrict__ xT) {
  __shared__ u16 ts[64 * 32];
  int b0 = (blockIdx.x >> 4) * 64;
  int d0 = (blockIdx.x & 15) * 32;
  int t = threadIdx.x;

  {
    int r = t >> 2, c = (t & 3) * 8;
    const float4* src = reinterpret_cast<const float4*>(x + (size_t)(b0 + r) * ND + d0 + c);
    float4 f0 = src[0], f1 = src[1];
    union { u16 u[8]; uint4 v; } pk;
    pk.u[0] = f2bf(f0.x); pk.u[1] = f2bf(f0.y); pk.u[2] = f2bf(f0.z); pk.u[3] = f2bf(f0.w);
    pk.u[4] = f2bf(f1.x); pk.u[5] = f2bf(f1.y); pk.u[6] = f2bf(f1.z); pk.u[7] = f2bf(f1.w);
    *reinterpret_cast<uint4*>(&ts[r * 32 + c]) = pk.v;
  }
  __syncthreads();
  {
    int d = t >> 3, bc = (t & 7) * 8;
    union { u16 u[8]; uint4 v; } ou;
#pragma unroll
    for (int j = 0; j < 8; ++j) ou.u[j] = ts[(bc + j) * 32 + d];
    *reinterpret_cast<uint4*>(xT + (size_t)(d0 + d) * NB + b0 + bc) = ou.v;
  }
}

// ---------------- fused attention ----------------
// grid 256 (one 32-row q-block per WG), 512 threads (8 waves)
// xbf: normalized rows [NB][ND]; xT: raw transposed [ND][NB]
__global__ __launch_bounds__(512, 2) void attn_kernel(const u16* __restrict__ xbf,
                                                      const u16* __restrict__ xT,
                                                      float* __restrict__ out) {
  __shared__ u16 Ks[KB * ND];   // [kv][d], byte ^ ((kv&7)<<4)
  __shared__ u16 Vt[ND * KB];   // [d][kv], byte ^ ((d&7)<<4)
  __shared__ u16 Pl[QB * KB];   // [q][kv], byte ^ ((q&7)<<4)
  __shared__ float Zpart[8 * 16];
  __shared__ float Zfin[QB];

  const int tid = threadIdx.x;
  const int w = tid >> 6;
  const int l = tid & 63;
  const int qb = blockIdx.x;

  const int qt = w & 1;    // phase-1 q sub-tile
  const int kvt = w >> 1;  // phase-1 kv sub-tile 0..3

  // ---- Q B-fragments straight from global (L2/L3-resident)
  bf16x8 qf[16];
  {
    size_t qrow = (size_t)(qb * QB + qt * 16 + (l & 15));
#pragma unroll
    for (int ks = 0; ks < 16; ++ks)
      qf[ks] = *reinterpret_cast<const bf16x8*>(xbf + qrow * ND + ks * 32 + (l >> 4) * 8);
  }

  // ---- staging maps
  const int k_kv = tid >> 3;        // 0..63
  const int k_dc = (tid & 7) * 64;  // K: 64 bf16 per thread
  const int v_d = tid >> 3;         // V: base d row (+64*it)
  const int v_kc = (tid & 7) * 8;   // V: 8 kv per thread per row

  // ---- preload tile 0
  uint4 kreg[8], vreg[8];
#pragma unroll
  for (int j = 0; j < 8; ++j)
    kreg[j] = *reinterpret_cast<const uint4*>(xbf + (size_t)k_kv * ND + k_dc + j * 8);
#pragma unroll
  for (int it = 0; it < 8; ++it)
    vreg[it] = *reinterpret_cast<const uint4*>(xT + (size_t)(v_d + it * 64) * NB + v_kc);

  f32x4 oacc[2][4];
#pragma unroll
  for (int a = 0; a < 2; ++a)
#pragma unroll
    for (int b = 0; b < 4; ++b) oacc[a][b] = (f32x4){0.f, 0.f, 0.f, 0.f};
  float zacc = 0.f;

  for (int t = 0; t < NT; ++t) {
    __syncthreads();  // (A) LDS free for restaging

    // K writes: b128, swizzled by kv
#pragma unroll
    for (int j = 0; j < 8; ++j) {
      int byte = ((k_kv * ND + k_dc + j * 8) * 2) ^ ((k_kv & 7) << 4);
      *reinterpret_cast<uint4*>((char*)Ks + byte) = kreg[j];
    }
    // V writes: b128, swizzled by d
#pragma unroll
    for (int it = 0; it < 8; ++it) {
      int d = v_d + it * 64;
      int byte = ((d * KB + v_kc) * 2) ^ ((d & 7) << 4);
      *reinterpret_cast<uint4*>((char*)Vt + byte) = vreg[it];
    }

    // prefetch tile t+1 (hides under phase1+2)
    if (t + 1 < NT) {
#pragma unroll
      for (int j = 0; j < 8; ++j)
        kreg[j] = *reinterpret_cast<const uint4*>(
            xbf + (size_t)((t + 1) * KB + k_kv) * ND + k_dc + j * 8);
#pragma unroll
      for (int it = 0; it < 8; ++it)
        vreg[it] = *reinterpret_cast<const uint4*>(
            xT + (size_t)(v_d + it * 64) * NB + (t + 1) * KB + v_kc);
    }
    __syncthreads();  // (B) staging visible

    // ---- phase 1 (swapped): S^T[kv16][q16] = K_kvt . Q_qt^T
    f32x4 acc = {0.f, 0.f, 0.f, 0.f};
    {
      int kvrow = kvt * 16 + (l & 15);
      int swz = (kvrow & 7) << 4;
      int base = kvrow * ND;
#pragma unroll
      for (int ks = 0; ks < 16; ++ks) {
        int byte = ((base + ks * 32 + (l >> 4) * 8) * 2) ^ swz;
        bf16x8 kf = *reinterpret_cast<const bf16x8*>((const char*)Ks + byte);
        acc = __builtin_amdgcn_mfma_f32_16x16x32_bf16(kf, qf[ks], acc, 0, 0, 0);
      }
    }
    // exp (cosine in [-1,1], no max needed), Z, pack P as bf16 pairs
    {
      float e0 = __expf(acc[0]), e1 = __expf(acc[1]);
      float e2 = __expf(acc[2]), e3 = __expf(acc[3]);
      zacc += (e0 + e1) + (e2 + e3);
      u32 p01, p23;
      asm("v_cvt_pk_bf16_f32 %0, %1, %2" : "=v"(p01) : "v"(e0), "v"(e1));
      asm("v_cvt_pk_bf16_f32 %0, %1, %2" : "=v"(p23) : "v"(e2), "v"(e3));
      int qrow = qt * 16 + (l & 15);
      int byte = ((qrow * KB + kvt * 16 + (l >> 4) * 4) * 2) ^ ((qrow & 7) << 4);
      uint2 pw = {p01, p23};
      *reinterpret_cast<uint2*>((char*)Pl + byte) = pw;
    }
    __syncthreads();  // (C) P ready

    // ---- phase 2: O += P . V   (wave owns d-block w*64, both q sub-tiles)
    {
      bf16x8 pa[2][2];
#pragma unroll
      for (int q2 = 0; q2 < 2; ++q2) {
        int qrow = q2 * 16 + (l & 15);
        int swz = (qrow & 7) << 4;
#pragma unroll
        for (int ks = 0; ks < 2; ++ks) {
          int byte = ((qrow * KB + ks * 32 + (l >> 4) * 8) * 2) ^ swz;
          pa[q2][ks] = *reinterpret_cast<const bf16x8*>((const char*)Pl + byte);
        }
      }
#pragma unroll
      for (int dt = 0; dt < 4; ++dt) {
        int drow = w * 64 + dt * 16 + (l & 15);
        int swz = (drow & 7) << 4;
#pragma unroll
        for (int ks = 0; ks < 2; ++ks) {
          int byte = ((drow * KB + ks * 32 + (l >> 4) * 8) * 2) ^ swz;
          bf16x8 vf = *reinterpret_cast<const bf16x8*>((const char*)Vt + byte);
#pragma unroll
          for (int q2 = 0; q2 < 2; ++q2)
            oacc[q2][dt] = __builtin_amdgcn_mfma_f32_16x16x32_bf16(pa[q2][ks], vf, oacc[q2][dt], 0, 0, 0);
        }
      }
    }
  }

  // ---- Z reduction: zacc per lane covers q = qt*16+(l&15); sum l>>4 groups, then kvt waves
  {
    float s = zacc;
    s += __shfl_xor(s, 16);
    s += __shfl_xor(s, 32);
    if (l < 16) Zpart[w * 16 + l] = s;
  }
  __syncthreads();
  if (tid < QB) {
    int qt_ = tid >> 4;
    float s = 0.f;
#pragma unroll
    for (int kv = 0; kv < 4; ++kv) s += Zpart[(kv * 2 + qt_) * 16 + (tid & 15)];
    Zfin[tid] = s;
  }
  __syncthreads();

  // ---- normalize + store f32
#pragma unroll
  for (int q2 = 0; q2 < 2; ++q2) {
    float rz[4];
#pragma unroll
    for (int r = 0; r < 4; ++r) rz[r] = 1.0f / Zfin[q2 * 16 + (l >> 4) * 4 + r];
#pragma unroll
    for (int dt = 0; dt < 4; ++dt) {
      int dcol = w * 64 + dt * 16 + (l & 15);
#pragma unroll
      for (int r = 0; r < 4; ++r) {
        size_t q = (size_t)(qb * QB + q2 * 16 + (l >> 4) * 4 + r);
        out[q * ND + dcol] = oacc[q2][dt][r] * rz[r];
      }
    }
  }
}

extern "C" void kernel_launch(void* const* d_in, const int* in_sizes, int n_in,
                              void* d_out, int out_size, void* d_ws, size_t ws_size,
                              hipStream_t stream) {
  const float* x = (const float*)d_in[0];
  float* outp = (float*)d_out;
  u16* xbf = (u16*)d_ws;                                    // 8 MB normalized bf16
  u16* xT = (u16*)((char*)d_ws + (size_t)NB * ND * 2);      // 8 MB raw transposed bf16

  prep_kernel<<<NB / 4, 256, 0, stream>>>(x, xbf);
  transpose_kernel<<<(NB / 64) * (ND / 32), 256, 0, stream>>>(x, xT);
  attn_kernel<<<NB / QB, 512, 0, stream>>>(xbf, xT, outp);
}

// Round 4
// 272.325 us; speedup vs baseline: 6.2033x; 6.2033x over previous
//
#include <hip/hip_runtime.h>

#define NB 8192
#define ND 512
#define QB 64
#define KB 32
#define NTILES (NB / KB)          // 256
#define TILE_BYTES (KB * ND * 2)  // 32768

typedef unsigned short u16;
typedef unsigned int u32;
typedef __attribute__((ext_vector_type(8))) short bf16x8;
typedef __attribute__((ext_vector_type(4))) float f32x4;

__device__ inline u16 f2bf(float f) {
  u32 u = __float_as_uint(f);
  return (u16)((u + 0x7fffu + ((u >> 16) & 1u)) >> 16);
}

// ---------------- prep1: reciprocal row norms ----------------
__global__ __launch_bounds__(256) void prep_norms(const float* __restrict__ x,
                                                  float* __restrict__ norms) {
  int row = blockIdx.x * 4 + (threadIdx.x >> 6);
  int lane = threadIdx.x & 63;
  const float4* xr = reinterpret_cast<const float4*>(x + (size_t)row * ND);
  float4 a = xr[lane];
  float4 b = xr[64 + lane];
  float ss = a.x * a.x + a.y * a.y + a.z * a.z + a.w * a.w +
             b.x * b.x + b.y * b.y + b.z * b.z + b.w * b.w;
  ss += __shfl_xor(ss, 1);  ss += __shfl_xor(ss, 2);  ss += __shfl_xor(ss, 4);
  ss += __shfl_xor(ss, 8);  ss += __shfl_xor(ss, 16); ss += __shfl_xor(ss, 32);
  if (lane == 0) norms[row] = 1.0f / fmaxf(sqrtf(ss), 1e-12f);
}

// ---------------- prep2: pre-swizzled bf16 tile images ----------------
// Kimg element (kv,d):  tile byte (kv*1024 + d*2)  ^ ((kv&7)<<4)   [d-contig granules]
// Vimg element (d,kv):  tile byte (d*64  + kv*2)   ^ ((d&7)<<4)    [kv-contig granules]
__global__ __launch_bounds__(256) void prep_images(const float* __restrict__ x,
                                                   u16* __restrict__ Kimg,
                                                   u16* __restrict__ Vimg) {
  __shared__ u16 Lt[TILE_BYTES / 2];  // Kimg-layout copy of this tile
  const int t = blockIdx.x;
  const int tid = threadIdx.x;

  {
    int kv = tid >> 3, d0 = (tid & 7) * 64;
    const float* src = x + (size_t)(t * KB + kv) * ND + d0;
    char* kbase = (char*)Kimg + (size_t)t * TILE_BYTES;
#pragma unroll
    for (int j = 0; j < 8; ++j) {
      float4 f0 = *(const float4*)(src + j * 8);
      float4 f1 = *(const float4*)(src + j * 8 + 4);
      union { u16 u[8]; uint4 v; } pk;
      pk.u[0] = f2bf(f0.x); pk.u[1] = f2bf(f0.y); pk.u[2] = f2bf(f0.z); pk.u[3] = f2bf(f0.w);
      pk.u[4] = f2bf(f1.x); pk.u[5] = f2bf(f1.y); pk.u[6] = f2bf(f1.z); pk.u[7] = f2bf(f1.w);
      int byte = (kv * 1024 + (d0 + j * 8) * 2) ^ ((kv & 7) << 4);
      *(uint4*)(kbase + byte) = pk.v;
      *(uint4*)((char*)Lt + byte) = pk.v;
    }
  }
  __syncthreads();
  {
    char* vbase = (char*)Vimg + (size_t)t * TILE_BYTES;
#pragma unroll
    for (int i = 0; i < 8; ++i) {
      int gid = tid + 256 * i;
      int d = gid >> 2, kv0 = (gid & 3) * 8;
      union { u16 u[8]; uint4 v; } o;
#pragma unroll
      for (int k = 0; k < 8; ++k) {
        int sb = ((kv0 + k) * 1024 + d * 2) ^ (((kv0 + k) & 7) << 4);
        o.u[k] = *(const u16*)((const char*)Lt + sb);
      }
      int byte = (d * 64 + kv0 * 2) ^ ((d & 7) << 4);
      *(uint4*)(vbase + byte) = o.v;
    }
  }
}

// ---------------- fused attention ----------------
// NCH=2: grid 256, partials per KV-half.  NCH=1: grid 128, direct out.
template <int NCH>
__global__ __launch_bounds__(512, 2) void attn_kernel(const float* __restrict__ x,
                                                      const u16* __restrict__ Kimg,
                                                      const u16* __restrict__ Vimg,
                                                      const float* __restrict__ norms,
                                                      float* __restrict__ Opart,
                                                      float* __restrict__ Zpart,
                                                      float* __restrict__ out) {
  __shared__ u16 Kl[2][TILE_BYTES / 2];
  __shared__ u16 Vl[2][TILE_BYTES / 2];
  __shared__ u16 Pl[QB * KB];  // byte = ((q*KB+kv)*2) ^ ((q&7)<<4)  (bijective)
  __shared__ float Zred[8 * 16];
  __shared__ float Zfin[QB];

  const int tid = threadIdx.x;
  const int w = tid >> 6;
  const int l = tid & 63;
  const int bid = blockIdx.x;

  int chunk, qblk;
  if constexpr (NCH == 2) {
    chunk = (bid >> 2) & 1;
    qblk = (bid & 3) * 32 + (bid >> 3);
  } else {
    chunk = 0;
    qblk = (bid & 7) * 16 + (bid >> 3);
  }
  const int CT = NTILES / NCH;
  const int tile0 = chunk * CT;

  const int qt = w & 3;    // phase-1 q sub-tile
  const int kvt = w >> 2;  // phase-1 kv sub-tile (0..1)

  // ---- Q fragments (normalized bf16 baked from f32)
  bf16x8 qf[16];
  {
    int qrow = qblk * QB + qt * 16 + (l & 15);
    float rnq = norms[qrow];
    const float* xr = x + (size_t)qrow * ND;
#pragma unroll
    for (int ks = 0; ks < 16; ++ks) {
      int d0 = ks * 32 + (l >> 4) * 8;
      float4 f0 = *(const float4*)(xr + d0);
      float4 f1 = *(const float4*)(xr + d0 + 4);
      union { u16 u[8]; bf16x8 v; } pk;
      pk.u[0] = f2bf(f0.x * rnq); pk.u[1] = f2bf(f0.y * rnq);
      pk.u[2] = f2bf(f0.z * rnq); pk.u[3] = f2bf(f0.w * rnq);
      pk.u[4] = f2bf(f1.x * rnq); pk.u[5] = f2bf(f1.y * rnq);
      pk.u[6] = f2bf(f1.z * rnq); pk.u[7] = f2bf(f1.w * rnq);
      qf[ks] = pk.v;
    }
  }

  auto stage = [&](int tg, int b) {
    size_t toff = (size_t)tg * TILE_BYTES;
#pragma unroll
    for (int j = 0; j < 4; ++j) {
      const char* src = (const char*)Kimg + toff + (w * 4 + j) * 1024 + l * 16;
      char* dst = (char*)&Kl[b][0] + (w * 4 + j) * 1024;
      __builtin_amdgcn_global_load_lds((const void*)src, (void*)dst, 16, 0, 0);
    }
#pragma unroll
    for (int j = 0; j < 4; ++j) {
      const char* src = (const char*)Vimg + toff + (w * 4 + j) * 1024 + l * 16;
      char* dst = (char*)&Vl[b][0] + (w * 4 + j) * 1024;
      __builtin_amdgcn_global_load_lds((const void*)src, (void*)dst, 16, 0, 0);
    }
  };

  stage(tile0, 0);

  f32x4 oacc[4][4];
#pragma unroll
  for (int a = 0; a < 4; ++a)
#pragma unroll
    for (int b = 0; b < 4; ++b) oacc[a][b] = (f32x4){0.f, 0.f, 0.f, 0.f};
  float zacc = 0.f;

  const int kv = kvt * 16 + (l & 15);
  const int rowbase = kv * 1024;
  const int kswz = (kv & 7) << 4;
  const int hi16 = (l >> 4) * 16;

  for (int t = 0; t < CT; ++t) {
    const int buf = t & 1;
    asm volatile("s_waitcnt vmcnt(0)" ::: "memory");
    __builtin_amdgcn_s_barrier();
    __builtin_amdgcn_sched_barrier(0);
    if (t + 1 < CT) stage(tile0 + t + 1, buf ^ 1);

    // ---- phase 1: S^T(kv16 x q16) = K . Q^T, two independent acc chains
    f32x4 acc0 = {0.f, 0.f, 0.f, 0.f}, acc1 = {0.f, 0.f, 0.f, 0.f};
    {
      const char* kb = (const char*)&Kl[buf][0];
#pragma unroll
      for (int ks = 0; ks < 16; ks += 2) {
        bf16x8 k0 = *(const bf16x8*)(kb + ((rowbase + ks * 64 + hi16) ^ kswz));
        bf16x8 k1 = *(const bf16x8*)(kb + ((rowbase + (ks + 1) * 64 + hi16) ^ kswz));
        acc0 = __builtin_amdgcn_mfma_f32_16x16x32_bf16(k0, qf[ks], acc0, 0, 0, 0);
        acc1 = __builtin_amdgcn_mfma_f32_16x16x32_bf16(k1, qf[ks + 1], acc1, 0, 0, 0);
      }
    }
    // ---- epilogue: cosine scale by rn_k, exp, Z, pack P
    {
      int kvbase = kvt * 16 + (l >> 4) * 4;
      float4 rn4 = *(const float4*)(norms + (tile0 + t) * KB + kvbase);
      float p0 = __expf((acc0[0] + acc1[0]) * rn4.x);
      float p1 = __expf((acc0[1] + acc1[1]) * rn4.y);
      float p2 = __expf((acc0[2] + acc1[2]) * rn4.z);
      float p3 = __expf((acc0[3] + acc1[3]) * rn4.w);
      zacc += (p0 + p1) + (p2 + p3);
      u32 w01, w23;
      asm("v_cvt_pk_bf16_f32 %0, %1, %2" : "=v"(w01) : "v"(p0), "v"(p1));
      asm("v_cvt_pk_bf16_f32 %0, %1, %2" : "=v"(w23) : "v"(p2), "v"(p3));
      int q = qt * 16 + (l & 15);
      int pbyte = ((q * KB + kvbase) * 2) ^ ((q & 7) << 4);
      *(uint2*)((char*)Pl + pbyte) = (uint2){w01, w23};
    }
    asm volatile("s_waitcnt lgkmcnt(0)" ::: "memory");
    __builtin_amdgcn_s_barrier();
    __builtin_amdgcn_sched_barrier(0);

    // ---- phase 2: O += P . V (wave owns d-block w*64; K-dim 32 = 1 mfma)
    {
      const char* plb = (const char*)Pl;
      bf16x8 pa[4];
#pragma unroll
      for (int q2 = 0; q2 < 4; ++q2) {
        int qr = q2 * 16 + (l & 15);
        pa[q2] = *(const bf16x8*)(plb + (((qr * KB) * 2 + hi16) ^ ((qr & 7) << 4)));
      }
      const char* vb = (const char*)&Vl[buf][0];
#pragma unroll
      for (int dt = 0; dt < 4; ++dt) {
        int d = w * 64 + dt * 16 + (l & 15);
        bf16x8 vf = *(const bf16x8*)(vb + ((d * 64 + hi16) ^ ((d & 7) << 4)));
#pragma unroll
        for (int q2 = 0; q2 < 4; ++q2)
          oacc[q2][dt] =
              __builtin_amdgcn_mfma_f32_16x16x32_bf16(pa[q2], vf, oacc[q2][dt], 0, 0, 0);
      }
    }
  }

  // ---- Z reduction
  {
    float s = zacc;
    s += __shfl_xor(s, 16);
    s += __shfl_xor(s, 32);
    if (l < 16) Zred[w * 16 + l] = s;
  }
  __syncthreads();

  if constexpr (NCH == 2) {
    if (tid < QB) {
      int qt_ = tid >> 4;
      float z = Zred[qt_ * 16 + (tid & 15)] + Zred[(qt_ + 4) * 16 + (tid & 15)];
      Zpart[chunk * NB + qblk * QB + tid] = z;
    }
    float* op = Opart + (size_t)chunk * NB * ND;
#pragma unroll
    for (int q2 = 0; q2 < 4; ++q2)
#pragma unroll
      for (int dt = 0; dt < 4; ++dt) {
        int d = w * 64 + dt * 16 + (l & 15);
#pragma unroll
        for (int r = 0; r < 4; ++r) {
          int q = qblk * QB + q2 * 16 + (l >> 4) * 4 + r;
          op[(size_t)q * ND + d] = oacc[q2][dt][r];
        }
      }
  } else {
    if (tid < QB) {
      int qt_ = tid >> 4;
      Zfin[tid] = Zred[qt_ * 16 + (tid & 15)] + Zred[(qt_ + 4) * 16 + (tid & 15)];
    }
    __syncthreads();
#pragma unroll
    for (int q2 = 0; q2 < 4; ++q2) {
      float rz[4];
#pragma unroll
      for (int r = 0; r < 4; ++r) rz[r] = 1.0f / Zfin[q2 * 16 + (l >> 4) * 4 + r];
#pragma unroll
      for (int dt = 0; dt < 4; ++dt) {
        int d = w * 64 + dt * 16 + (l & 15);
#pragma unroll
        for (int r = 0; r < 4; ++r) {
          int q = qblk * QB + q2 * 16 + (l >> 4) * 4 + r;
          out[(size_t)q * ND + d] = oacc[q2][dt][r] * rz[r];
        }
      }
    }
  }
}

// ---------------- combine (fast path): out = (O0+O1)/(Z0+Z1) ----------------
__global__ __launch_bounds__(256) void combine_kernel(const float* __restrict__ Opart,
                                                      const float* __restrict__ Zpart,
                                                      float* __restrict__ out) {
  size_t idx = ((size_t)blockIdx.x * 256 + threadIdx.x) * 4;
  int row = (int)(idx >> 9);
  float rz = 1.0f / (Zpart[row] + Zpart[NB + row]);
  float4 a = *(const float4*)(Opart + idx);
  float4 b = *(const float4*)(Opart + (size_t)NB * ND + idx);
  float4 o = {(a.x + b.x) * rz, (a.y + b.y) * rz, (a.z + b.z) * rz, (a.w + b.w) * rz};
  *(float4*)(out + idx) = o;
}

extern "C" void kernel_launch(void* const* d_in, const int* in_sizes, int n_in,
                              void* d_out, int out_size, void* d_ws, size_t ws_size,
                              hipStream_t stream) {
  const float* x = (const float*)d_in[0];
  float* outp = (float*)d_out;

  char* ws = (char*)d_ws;
  const size_t img_bytes = (size_t)NB * ND * 2;  // 8 MB each
  float* norms = (float*)ws;                     // 32 KB
  u16* Kimg = (u16*)(ws + 32768);
  u16* Vimg = (u16*)(ws + 32768 + img_bytes);
  size_t base = 32768 + 2 * img_bytes;           // 16.03 MB (proven-safe extent)
  float* Zpart = (float*)(ws + base);            // 64 KB
  float* Opart = (float*)(ws + base + 65536);    // 32 MB
  size_t need = base + 65536 + (size_t)2 * NB * ND * 4;

  prep_norms<<<NB / 4, 256, 0, stream>>>(x, norms);
  prep_images<<<NTILES, 256, 0, stream>>>(x, Kimg, Vimg);
  if (ws_size >= need) {
    attn_kernel<2><<<256, 512, 0, stream>>>(x, Kimg, Vimg, norms, Opart, Zpart, nullptr);
    combine_kernel<<<(NB * ND) / 1024, 256, 0, stream>>>(Opart, Zpart, outp);
  } else {
    attn_kernel<1><<<128, 512, 0, stream>>>(x, Kimg, Vimg, norms, nullptr, nullptr, outp);
  }
}